// Round 7
// baseline (372.618 us; speedup 1.0000x reference)
//
#include <hip/hip_runtime.h>
#include <hip/hip_bf16.h>

#define SEQ 2048
#define DM  1024
#define NH  16
#define HDM 64

typedef __hip_bfloat16 bf16;
typedef __bf16 bhalf8 __attribute__((ext_vector_type(8)));
typedef float floatx4 __attribute__((ext_vector_type(4)));

__device__ __forceinline__ void async_cp16(const void* g, void* l) {
  __builtin_amdgcn_global_load_lds(
      (const __attribute__((address_space(1))) void*)g,
      (__attribute__((address_space(3))) void*)l, 16, 0, 0);
}

// ---- convert: x f32 -> bf16 [2048*1024]; rel f32 -> bf16 padded [4096][64]
__global__ __launch_bounds__(256) void convert_inputs(
    const float* __restrict__ x, const float* __restrict__ T,
    bf16* __restrict__ xbf, bf16* __restrict__ Tbf)
{
  const int c = blockIdx.x * 256 + threadIdx.x;
  if (c < 524288) {                       // x: 2M elems, 4 per thread
    float4 v = *(const float4*)&x[(size_t)c * 4];
    union { bf16 h[4]; float2 f; } u;
    u.h[0] = __float2bfloat16(v.x); u.h[1] = __float2bfloat16(v.y);
    u.h[2] = __float2bfloat16(v.z); u.h[3] = __float2bfloat16(v.w);
    *(float2*)&xbf[(size_t)c * 4] = u.f;
  } else {                                 // T: 4096*64 padded (row 4095 dup)
    int ct = c - 524288;                   // [0, 65536)
    union { bf16 h[4]; float2 f; } u;
#pragma unroll
    for (int e = 0; e < 4; ++e) {
      int se = ct * 4 + e;
      if (se >= 4095 * 64) se -= 64;
      u.h[e] = __float2bfloat16(T[se]);
    }
    *(float2*)&Tbf[(size_t)ct * 4] = u.f;
  }
}

// ---- transpose weights: W f32 [k][n] -> Wt bf16 [n][k]; z selects matrix
__global__ __launch_bounds__(256) void transpose_w(
    const float* __restrict__ W0, const float* __restrict__ W1,
    const float* __restrict__ W2, const float* __restrict__ W3,
    bf16* __restrict__ WtBase)
{
  __shared__ float tile[64][69];
  const int z = blockIdx.z;
  const float* W = (z == 0) ? W0 : (z == 1) ? W1 : (z == 2) ? W2 : W3;
  bf16* Wt = WtBase + (size_t)z * DM * DM;
  const int kb = blockIdx.x * 64, nb = blockIdx.y * 64;
  const int tid = threadIdx.x;
  const int r = tid >> 4, c4 = (tid & 15) * 4;
#pragma unroll
  for (int rr = 0; rr < 4; ++rr) {
    float4 v = *(const float4*)&W[(size_t)(kb + rr * 16 + r) * DM + nb + c4];
    tile[rr * 16 + r][c4 + 0] = v.x; tile[rr * 16 + r][c4 + 1] = v.y;
    tile[rr * 16 + r][c4 + 2] = v.z; tile[rr * 16 + r][c4 + 3] = v.w;
  }
  __syncthreads();
  const int w = tid >> 6, l = tid & 63;
#pragma unroll
  for (int i = 0; i < 16; ++i) {
    int n = nb + w * 16 + i;
    Wt[(size_t)n * DM + kb + l] = __float2bfloat16(tile[l][w * 16 + i]);
  }
}

// ---- MFMA GEMM core: acc[4][4] += A[128x1024] tile @ Bt[n][k]^T tile
__device__ __forceinline__ void gemm_core(
    const bf16* __restrict__ A, const bf16* __restrict__ Bt,
    bf16* As, bf16* Bs, int bm, int bn, floatx4 (&acc)[4][4])
{
  const int tid = threadIdx.x;
  const int lane = tid & 63;
  const int w = tid >> 6;
  const int wx = w & 1, wy = w >> 1;
  const int ln15 = lane & 15, quad = lane >> 4;

  for (int k0 = 0; k0 < DM; k0 += 32) {
#pragma unroll
    for (int t = 0; t < 2; ++t) {
      int cbase = w * 128 + t * 64;        // wave-uniform chunk base
      int c = cbase + lane;                // 16B chunk id, 512 total
      int row = c >> 2, col = (c & 3) * 8;
      async_cp16(A  + (size_t)(bm + row) * DM + k0 + col, As + cbase * 8);
      async_cp16(Bt + (size_t)(bn + row) * DM + k0 + col, Bs + cbase * 8);
    }
    __syncthreads();                        // drains vmcnt before reads
    bhalf8 af[4], bfr[4];
#pragma unroll
    for (int i = 0; i < 4; ++i)
      af[i] = *(bhalf8*)&As[(wy * 64 + i * 16 + ln15) * 32 + quad * 8];
#pragma unroll
    for (int j = 0; j < 4; ++j)
      bfr[j] = *(bhalf8*)&Bs[(wx * 64 + j * 16 + ln15) * 32 + quad * 8];
#pragma unroll
    for (int i = 0; i < 4; ++i)
#pragma unroll
      for (int j = 0; j < 4; ++j)
        acc[i][j] = __builtin_amdgcn_mfma_f32_16x16x32_bf16(af[i], bfr[j], acc[i][j], 0, 0, 0);
    __syncthreads();                        // protect LDS before next stage
  }
}

// ---- QKV projection, batched z=0,1,2. Out: z<2 head-major; z==2 transposed [D][S]
__global__ __launch_bounds__(256) void gemm_qkv(
    const bf16* __restrict__ A, const bf16* __restrict__ Wt3,
    const float* __restrict__ bq, const float* __restrict__ bk,
    const float* __restrict__ bv, bf16* __restrict__ outbase)
{
  __shared__ __align__(16) bf16 As[128 * 32];
  __shared__ __align__(16) bf16 Bs[128 * 32];
  const int z = blockIdx.z;
  const bf16* Bt = Wt3 + (size_t)z * DM * DM;
  const float* bias = (z == 0) ? bq : (z == 1) ? bk : bv;
  bf16* C = outbase + (size_t)z * SEQ * DM;
  const int bm = blockIdx.y * 128, bn = blockIdx.x * 128;
  floatx4 acc[4][4];
#pragma unroll
  for (int i = 0; i < 4; ++i)
#pragma unroll
    for (int j = 0; j < 4; ++j) acc[i][j] = (floatx4){0.f, 0.f, 0.f, 0.f};
  gemm_core(A, Bt, As, Bs, bm, bn, acc);

  const int lane = threadIdx.x & 63;
  const int w = threadIdx.x >> 6;
  const int wx = w & 1, wy = w >> 1;
  const int ln15 = lane & 15, quad = lane >> 4;
#pragma unroll
  for (int i = 0; i < 4; ++i)
#pragma unroll
    for (int j = 0; j < 4; ++j) {
      int col = bn + wx * 64 + j * 16 + ln15;
      float bv_ = bias[col];
#pragma unroll
      for (int r = 0; r < 4; ++r) {
        int row = bm + wy * 64 + i * 16 + quad * 4 + r;
        float v = acc[i][j][r] + bv_;
        if (z < 2)
          C[((size_t)(col >> 6) * SEQ + row) * HDM + (col & 63)] = __float2bfloat16(v);
        else
          C[(size_t)col * SEQ + row] = __float2bfloat16(v);
      }
    }
}

// ---- output projection: f32 out row-major
__global__ __launch_bounds__(256) void gemm_out(
    const bf16* __restrict__ A, const bf16* __restrict__ Bt,
    const float* __restrict__ bias, float* __restrict__ C)
{
  __shared__ __align__(16) bf16 As[128 * 32];
  __shared__ __align__(16) bf16 Bs[128 * 32];
  const int bm = blockIdx.y * 128, bn = blockIdx.x * 128;
  floatx4 acc[4][4];
#pragma unroll
  for (int i = 0; i < 4; ++i)
#pragma unroll
    for (int j = 0; j < 4; ++j) acc[i][j] = (floatx4){0.f, 0.f, 0.f, 0.f};
  gemm_core(A, Bt, As, Bs, bm, bn, acc);

  const int lane = threadIdx.x & 63;
  const int w = threadIdx.x >> 6;
  const int wx = w & 1, wy = w >> 1;
  const int ln15 = lane & 15, quad = lane >> 4;
#pragma unroll
  for (int i = 0; i < 4; ++i)
#pragma unroll
    for (int j = 0; j < 4; ++j) {
      int col = bn + wx * 64 + j * 16 + ln15;
      float bv_ = bias[col];
#pragma unroll
      for (int r = 0; r < 4; ++r) {
        int row = bm + wy * 64 + i * 16 + quad * 4 + r;
        C[(size_t)row * DM + col] = acc[i][j][r] + bv_;
      }
    }
}

// ---- Flash attention, key-split x2, BARRIER-FREE inner loop.
// All MFMA A/B fragments load directly from global (16B contiguous under the
// chosen layouts); LDS holds only the two wave-private transposes:
// S2 diagonal scatter (f32 [64][66]) and P C->A round-trip ([64][72]).
// LDS 26112 B -> 4+ blocks/CU, zero __syncthreads in the loop.
__global__ __launch_bounds__(256, 4) void attn_flash(
    const bf16* __restrict__ Q, const bf16* __restrict__ K,
    const bf16* __restrict__ Vt, const bf16* __restrict__ Tb,
    bf16* __restrict__ Opart, float* __restrict__ ml)
{
  const int i0   = blockIdx.x * 64;
  const int h    = blockIdx.y;
  const int z    = blockIdx.z;
  const int tid  = threadIdx.x;
  const int lane = tid & 63;
  const int wrow = (tid >> 6) * 16;   // wave's 16-row slice of the Q tile
  const int ln15 = lane & 15;
  const int quad = lane >> 4;

  __shared__ __align__(16) unsigned char smem[26112];
  float* S2c = (float*)smem;                // [64][66] f32, diagonal layout
  bf16*  Ps  = (bf16*)(smem + 16896);       // [64][72]

  const bf16* Qg = Q  + ((size_t)h * SEQ + i0) * HDM;
  const bf16* Kg = K  + (size_t)h * SEQ * HDM;
  const bf16* Vg = Vt + (size_t)h * HDM * SEQ;

  // Q A-fragments: row wrow+ln15, k = quad*8 (+32) — direct global 16B loads
  const bhalf8 aq0 = *(const bhalf8*)&Qg[(size_t)(wrow + ln15) * HDM + quad * 8];
  const bhalf8 aq1 = *(const bhalf8*)&Qg[(size_t)(wrow + ln15) * HDM + quad * 8 + 32];

  floatx4 o[4];
  float mrow[4], lrow[4];
#pragma unroll
  for (int c = 0; c < 4; ++c) o[c] = (floatx4){0.f, 0.f, 0.f, 0.f};
#pragma unroll
  for (int r = 0; r < 4; ++r) { mrow[r] = -1e30f; lrow[r] = 0.f; }

  for (int jt = z * 16; jt < z * 16 + 16; ++jt) {
    const int j0 = jt * 64;
    const int rbase = i0 - j0 + SEQ - HDM;   // in [0, 3968]

    // S2 = Q_tile @ T_band^T (16x128 per wave), B-frags direct from global.
    // Scatter to diagonal layout: (row, t) -> S2c[row][row+63-t], f32 exact.
#pragma unroll
    for (int ct = 0; ct < 8; ++ct) {
      const bf16* tr = Tb + (size_t)(rbase + ct * 16 + ln15) * HDM + quad * 8;
      bhalf8 b0 = *(const bhalf8*)tr;
      bhalf8 b1 = *(const bhalf8*)(tr + 32);
      floatx4 a = (floatx4){0.f, 0.f, 0.f, 0.f};
      a = __builtin_amdgcn_mfma_f32_16x16x32_bf16(aq0, b0, a, 0, 0, 0);
      a = __builtin_amdgcn_mfma_f32_16x16x32_bf16(aq1, b1, a, 0, 0, 0);
#pragma unroll
      for (int r = 0; r < 4; ++r) {
        int row = wrow + quad * 4 + r;
        int col = row + 63 - (ct * 16 + ln15);
        if ((unsigned)col < 64u) S2c[row * 66 + col] = a[r];
      }
    }

    // S1 = Q K^T (B-frags direct), add rel band (contiguous), online softmax
    float sc[4][4];
#pragma unroll
    for (int ct = 0; ct < 4; ++ct) {
      const bf16* kr = Kg + (size_t)(j0 + ct * 16 + ln15) * HDM + quad * 8;
      bhalf8 b0 = *(const bhalf8*)kr;
      bhalf8 b1 = *(const bhalf8*)(kr + 32);
      floatx4 a = (floatx4){0.f, 0.f, 0.f, 0.f};
      a = __builtin_amdgcn_mfma_f32_16x16x32_bf16(aq0, b0, a, 0, 0, 0);
      a = __builtin_amdgcn_mfma_f32_16x16x32_bf16(aq1, b1, a, 0, 0, 0);
#pragma unroll
      for (int r = 0; r < 4; ++r) {
        int row = wrow + quad * 4 + r;
        sc[ct][r] = a[r] * 0.125f + S2c[row * 66 + ct * 16 + ln15];
      }
    }
#pragma unroll
    for (int r = 0; r < 4; ++r) {
      float tm = fmaxf(fmaxf(sc[0][r], sc[1][r]), fmaxf(sc[2][r], sc[3][r]));
      tm = fmaxf(tm, __shfl_xor(tm, 1));
      tm = fmaxf(tm, __shfl_xor(tm, 2));
      tm = fmaxf(tm, __shfl_xor(tm, 4));
      tm = fmaxf(tm, __shfl_xor(tm, 8));
      float mn = fmaxf(mrow[r], tm);
      float alpha = __expf(mrow[r] - mn);
      mrow[r] = mn;
      float rs = 0.f;
#pragma unroll
      for (int ct = 0; ct < 4; ++ct) {
        float p = __expf(sc[ct][r] - mn);
        sc[ct][r] = p;
        rs += p;
      }
      rs += __shfl_xor(rs, 1); rs += __shfl_xor(rs, 2);
      rs += __shfl_xor(rs, 4); rs += __shfl_xor(rs, 8);
      lrow[r] = lrow[r] * alpha + rs;
#pragma unroll
      for (int ct = 0; ct < 4; ++ct) o[ct][r] *= alpha;
    }

    // P: C-layout regs -> LDS (wave-private rows) -> A-layout frags
#pragma unroll
    for (int ct = 0; ct < 4; ++ct)
#pragma unroll
      for (int r = 0; r < 4; ++r)
        Ps[(wrow + quad * 4 + r) * 72 + ct * 16 + ln15] = __float2bfloat16(sc[ct][r]);

    bhalf8 ap0 = *(bhalf8*)&Ps[(wrow + ln15) * 72 + quad * 8];
    bhalf8 ap1 = *(bhalf8*)&Ps[(wrow + ln15) * 72 + quad * 8 + 32];

    // PV: B-frags direct from V^T [d][s]
#pragma unroll
    for (int ct = 0; ct < 4; ++ct) {
      const bf16* vr = Vg + (size_t)(ct * 16 + ln15) * SEQ + j0 + quad * 8;
      bhalf8 b0 = *(const bhalf8*)vr;
      bhalf8 b1 = *(const bhalf8*)(vr + 32);
      o[ct] = __builtin_amdgcn_mfma_f32_16x16x32_bf16(ap0, b0, o[ct], 0, 0, 0);
      o[ct] = __builtin_amdgcn_mfma_f32_16x16x32_bf16(ap1, b1, o[ct], 0, 0, 0);
    }
  }

  // epilogue: locally-normalized partial + (m,l)
  bf16* Oz = Opart + (size_t)z * SEQ * DM;
#pragma unroll
  for (int r = 0; r < 4; ++r) {
    float inv = 1.f / lrow[r];
    int row = i0 + wrow + quad * 4 + r;
#pragma unroll
    for (int ct = 0; ct < 4; ++ct)
      Oz[(size_t)row * DM + h * HDM + ct * 16 + ln15] =
          __float2bfloat16(o[ct][r] * inv);
    if (ln15 == 0) {
      float* mlp = ml + (((size_t)z * NH + h) * SEQ + row) * 2;
      mlp[0] = mrow[r];
      mlp[1] = lrow[r];
    }
  }
}

// ---- merge the two key-halves: O = w0*O0n + w1*O1n
__global__ __launch_bounds__(256) void attn_merge(
    const bf16* __restrict__ O0, const bf16* __restrict__ O1,
    const float* __restrict__ ml, bf16* __restrict__ O)
{
  const int i = blockIdx.x;
  const int tid = threadIdx.x;
  __shared__ float w0s[NH], w1s[NH];
  if (tid < NH) {
    const float* p0 = ml + (((size_t)0 * NH + tid) * SEQ + i) * 2;
    const float* p1 = ml + (((size_t)1 * NH + tid) * SEQ + i) * 2;
    float m0 = p0[0], l0 = p0[1], m1 = p1[0], l1 = p1[1];
    float m = fmaxf(m0, m1);
    float a = l0 * __expf(m0 - m), b = l1 * __expf(m1 - m);
    float inv = 1.f / (a + b);
    w0s[tid] = a * inv; w1s[tid] = b * inv;
  }
  __syncthreads();
  const int d = tid * 4;
  const float w0 = w0s[d >> 6], w1 = w1s[d >> 6];
  union { bf16 h[4]; float2 f; } a0, a1, ov;
  a0.f = *(const float2*)&O0[(size_t)i * DM + d];
  a1.f = *(const float2*)&O1[(size_t)i * DM + d];
#pragma unroll
  for (int e = 0; e < 4; ++e)
    ov.h[e] = __float2bfloat16(w0 * __bfloat162float(a0.h[e]) +
                               w1 * __bfloat162float(a1.h[e]));
  *(float2*)&O[(size_t)i * DM + d] = ov.f;
}

extern "C" void kernel_launch(void* const* d_in, const int* in_sizes, int n_in,
                              void* d_out, int out_size, void* d_ws, size_t ws_size,
                              hipStream_t stream) {
  const float* x   = (const float*)d_in[0];
  const float* Wq  = (const float*)d_in[1];
  const float* bq  = (const float*)d_in[2];
  const float* Wk  = (const float*)d_in[3];
  const float* bk  = (const float*)d_in[4];
  const float* Wv  = (const float*)d_in[5];
  const float* bv  = (const float*)d_in[6];
  const float* Wo  = (const float*)d_in[7];
  const float* bo  = (const float*)d_in[8];
  const float* rel = (const float*)d_in[9];
  float* out = (float*)d_out;

  const size_t SD = (size_t)SEQ * DM;      // 2M elems
  bf16* qws = (bf16*)d_ws;                 // [H][S][64]
  bf16* kws = qws + SD;                    // [H][S][64]
  bf16* vws = kws + SD;                    // Vt [D][S]
  bf16* ows = vws + SD;                    // [S][D] merged attn out
  bf16* xbf = ows + SD;                    // [S][D]
  bf16* wt  = xbf + SD;                    // 4 x [n][k] (q,k,v,o)
  bf16* tbf = wt + 4 * (size_t)DM * DM;    // [4096][64]
  bf16* opart = tbf + (size_t)4096 * HDM;  // 2 x [S][D] partials
  float* ml   = (float*)(opart + 2 * SD);  // [2][NH][SEQ][2]

  convert_inputs<<<2304, 256, 0, stream>>>(x, rel, xbf, tbf);
  transpose_w<<<dim3(16, 16, 4), 256, 0, stream>>>(Wq, Wk, Wv, Wo, wt);
  gemm_qkv<<<dim3(8, 16, 3), 256, 0, stream>>>(xbf, wt, bq, bk, bv, qws);
  attn_flash<<<dim3(SEQ / 64, NH, 2), 256, 0, stream>>>(qws, kws, vws, tbf,
                                                        opart, ml);
  attn_merge<<<SEQ, 256, 0, stream>>>(opart, opart + SD, ml, ows);
  gemm_out<<<dim3(8, 16), 256, 0, stream>>>(ows, wt + 3 * (size_t)DM * DM, bo, out);
}

// Round 8
// 234.992 us; speedup vs baseline: 1.5857x; 1.5857x over previous
//
#include <hip/hip_runtime.h>
#include <hip/hip_bf16.h>

#define SEQ 2048
#define DM  1024
#define NH  16
#define HDM 64

typedef __hip_bfloat16 bf16;
typedef __bf16 bhalf8 __attribute__((ext_vector_type(8)));
typedef float floatx4 __attribute__((ext_vector_type(4)));

__device__ __forceinline__ void async_cp16(const void* g, void* l) {
  __builtin_amdgcn_global_load_lds(
      (const __attribute__((address_space(1))) void*)g,
      (__attribute__((address_space(3))) void*)l, 16, 0, 0);
}

// ---- fused prep: x f32->bf16; rel f32->bf16 padded [4096][64]; W transpose
// grid: [0,2048) x-convert | [2048,2304) T-convert | [2304,3328) transpose
__global__ __launch_bounds__(256) void prep(
    const float* __restrict__ x, const float* __restrict__ T,
    const float* __restrict__ W0, const float* __restrict__ W1,
    const float* __restrict__ W2, const float* __restrict__ W3,
    bf16* __restrict__ xbf, bf16* __restrict__ Tbf, bf16* __restrict__ WtBase)
{
  __shared__ float tile[64][69];
  const int b = blockIdx.x;
  const int tid = threadIdx.x;
  if (b < 2048) {
    int c = b * 256 + tid;                 // 4 elems/thread
    float4 v = *(const float4*)&x[(size_t)c * 4];
    union { bf16 h[4]; float2 f; } u;
    u.h[0] = __float2bfloat16(v.x); u.h[1] = __float2bfloat16(v.y);
    u.h[2] = __float2bfloat16(v.z); u.h[3] = __float2bfloat16(v.w);
    *(float2*)&xbf[(size_t)c * 4] = u.f;
  } else if (b < 2304) {
    int ct = (b - 2048) * 256 + tid;       // [0, 65536)
    union { bf16 h[4]; float2 f; } u;
#pragma unroll
    for (int e = 0; e < 4; ++e) {
      int se = ct * 4 + e;
      if (se >= 4095 * 64) se -= 64;       // pad row 4095 = dup of 4094
      u.h[e] = __float2bfloat16(T[se]);
    }
    *(float2*)&Tbf[(size_t)ct * 4] = u.f;
  } else {
    int tb = b - 2304;                     // [0, 1024)
    int z = tb >> 8, rem = tb & 255;
    const float* W = (z == 0) ? W0 : (z == 1) ? W1 : (z == 2) ? W2 : W3;
    bf16* Wt = WtBase + (size_t)z * DM * DM;
    const int kb = (rem >> 4) * 64, nb = (rem & 15) * 64;
    const int r = tid >> 4, c4 = (tid & 15) * 4;
#pragma unroll
    for (int rr = 0; rr < 4; ++rr) {
      float4 v = *(const float4*)&W[(size_t)(kb + rr * 16 + r) * DM + nb + c4];
      tile[rr * 16 + r][c4 + 0] = v.x; tile[rr * 16 + r][c4 + 1] = v.y;
      tile[rr * 16 + r][c4 + 2] = v.z; tile[rr * 16 + r][c4 + 3] = v.w;
    }
    __syncthreads();
    const int w = tid >> 6, l = tid & 63;
#pragma unroll
    for (int i = 0; i < 16; ++i) {
      int n = nb + w * 16 + i;
      Wt[(size_t)n * DM + kb + l] = __float2bfloat16(tile[l][w * 16 + i]);
    }
  }
}

// ---- MFMA GEMM core, tile M=64 x N=128, BK=32 (m97-style layouts).
// acc[2][4] per wave; waves 2x2 (wy: 32-row half, wx: 64-col half).
__device__ __forceinline__ void gemm64_core(
    const bf16* __restrict__ A, const bf16* __restrict__ Bt,
    bf16* As, bf16* Bs, int bm, int bn, floatx4 (&acc)[2][4])
{
  const int tid = threadIdx.x;
  const int lane = tid & 63;
  const int w = tid >> 6;
  const int wx = w & 1, wy = w >> 1;
  const int ln15 = lane & 15, quad = lane >> 4;

  for (int k0 = 0; k0 < DM; k0 += 32) {
    {
      int c = w * 64 + lane;               // A chunks [0,256)
      int row = c >> 2, col = (c & 3) * 8;
      async_cp16(A + (size_t)(bm + row) * DM + k0 + col, As + c * 8);
      int cb0 = w * 64 + lane;             // B chunks [0,256)
      int r0 = cb0 >> 2, c0 = (cb0 & 3) * 8;
      async_cp16(Bt + (size_t)(bn + r0) * DM + k0 + c0, Bs + cb0 * 8);
      int cb1 = 256 + w * 64 + lane;       // B chunks [256,512)
      int r1 = cb1 >> 2, c1 = (cb1 & 3) * 8;
      async_cp16(Bt + (size_t)(bn + r1) * DM + k0 + c1, Bs + cb1 * 8);
    }
    __syncthreads();
    bhalf8 af[2], bfr[4];
#pragma unroll
    for (int i = 0; i < 2; ++i)
      af[i] = *(bhalf8*)&As[(wy * 32 + i * 16 + ln15) * 32 + quad * 8];
#pragma unroll
    for (int j = 0; j < 4; ++j)
      bfr[j] = *(bhalf8*)&Bs[(wx * 64 + j * 16 + ln15) * 32 + quad * 8];
#pragma unroll
    for (int i = 0; i < 2; ++i)
#pragma unroll
      for (int j = 0; j < 4; ++j)
        acc[i][j] = __builtin_amdgcn_mfma_f32_16x16x32_bf16(af[i], bfr[j], acc[i][j], 0, 0, 0);
    __syncthreads();
  }
}

// ---- QKV projection, z=0,1,2. Out: z<2 head-major [H][S][64]; z==2 Vt [D][S]
__global__ __launch_bounds__(256) void gemm_qkv(
    const bf16* __restrict__ A, const bf16* __restrict__ Wt3,
    const float* __restrict__ bq, const float* __restrict__ bk,
    const float* __restrict__ bv, bf16* __restrict__ outbase)
{
  __shared__ __align__(16) bf16 As[64 * 32];
  __shared__ __align__(16) bf16 Bs[128 * 32];
  const int z = blockIdx.z;
  const bf16* Bt = Wt3 + (size_t)z * DM * DM;
  const float* bias = (z == 0) ? bq : (z == 1) ? bk : bv;
  bf16* C = outbase + (size_t)z * SEQ * DM;
  const int bm = blockIdx.y * 64, bn = blockIdx.x * 128;
  floatx4 acc[2][4];
#pragma unroll
  for (int i = 0; i < 2; ++i)
#pragma unroll
    for (int j = 0; j < 4; ++j) acc[i][j] = (floatx4){0.f, 0.f, 0.f, 0.f};
  gemm64_core(A, Bt, As, Bs, bm, bn, acc);

  const int lane = threadIdx.x & 63;
  const int w = threadIdx.x >> 6;
  const int wx = w & 1, wy = w >> 1;
  const int ln15 = lane & 15, quad = lane >> 4;
#pragma unroll
  for (int i = 0; i < 2; ++i)
#pragma unroll
    for (int j = 0; j < 4; ++j) {
      int col = bn + wx * 64 + j * 16 + ln15;
      float bv_ = bias[col];
#pragma unroll
      for (int r = 0; r < 4; ++r) {
        int row = bm + wy * 32 + i * 16 + quad * 4 + r;
        float v = acc[i][j][r] + bv_;
        if (z < 2)
          C[((size_t)(col >> 6) * SEQ + row) * HDM + (col & 63)] = __float2bfloat16(v);
        else
          C[(size_t)col * SEQ + row] = __float2bfloat16(v);
      }
    }
}

// ---- output projection: f32 out row-major
__global__ __launch_bounds__(256) void gemm_out(
    const bf16* __restrict__ A, const bf16* __restrict__ Bt,
    const float* __restrict__ bias, float* __restrict__ C)
{
  __shared__ __align__(16) bf16 As[64 * 32];
  __shared__ __align__(16) bf16 Bs[128 * 32];
  const int bm = blockIdx.y * 64, bn = blockIdx.x * 128;
  floatx4 acc[2][4];
#pragma unroll
  for (int i = 0; i < 2; ++i)
#pragma unroll
    for (int j = 0; j < 4; ++j) acc[i][j] = (floatx4){0.f, 0.f, 0.f, 0.f};
  gemm64_core(A, Bt, As, Bs, bm, bn, acc);

  const int lane = threadIdx.x & 63;
  const int w = threadIdx.x >> 6;
  const int wx = w & 1, wy = w >> 1;
  const int ln15 = lane & 15, quad = lane >> 4;
#pragma unroll
  for (int i = 0; i < 2; ++i)
#pragma unroll
    for (int j = 0; j < 4; ++j) {
      int col = bn + wx * 64 + j * 16 + ln15;
      float bv_ = bias[col];
#pragma unroll
      for (int r = 0; r < 4; ++r) {
        int row = bm + wy * 32 + i * 16 + quad * 4 + r;
        C[(size_t)row * DM + col] = acc[i][j][r] + bv_;
      }
    }
}

// ---- Flash attention, key-split x2, f32 diagonal-scatter S2 with BAND CARRY.
// Tile jt's band rows [rbase+64, rbase+128) == tile jt+1's [rbase, rbase+64):
// keep last iter's fresh 64-col band output in registers; per iter compute
// only the fresh half (8 MFMAs instead of 16, Ts staging halved).
// LDS 44544 B -> 3 blocks/CU.
__global__ __launch_bounds__(256) void attn_flash(
    const bf16* __restrict__ Q, const bf16* __restrict__ K,
    const bf16* __restrict__ Vt, const bf16* __restrict__ Tb,
    bf16* __restrict__ Opart, float* __restrict__ ml)
{
  const int i0   = blockIdx.x * 64;
  const int h    = blockIdx.y;
  const int z    = blockIdx.z;
  const int tid  = threadIdx.x;
  const int lane = tid & 63;
  const int wrow = (tid >> 6) * 16;
  const int ln15 = lane & 15;
  const int quad = lane >> 4;

  __shared__ __align__(16) unsigned char smem[44544];
  bf16*  Ks  = (bf16*)smem;                 // [64][72]
  bf16*  Vs  = (bf16*)(smem + 9216);        // [64][72], [d][j]
  bf16*  Ts  = (bf16*)(smem + 18432);       // [64][72]
  bf16*  Ps  = (bf16*)(smem + 18432);       // [64][72], overlaps Ts (barriered)
  float* S2c = (float*)(smem + 27648);      // [64][66] f32, diagonal layout
  bf16*  Qs  = (bf16*)(smem + 27648);       // [64][72], overlaps S2c (pre-loop)

  const bf16* Qg = Q  + ((size_t)h * SEQ + i0) * HDM;
  const bf16* Kg = K  + (size_t)h * SEQ * HDM;
  const bf16* Vg = Vt + (size_t)h * HDM * SEQ;

#pragma unroll
  for (int t = 0; t < 2; ++t) {
    int id = tid + t * 256;
    int r = id >> 3, c = (id & 7) * 8;
    *(float4*)&Qs[r * 72 + c] = *(const float4*)&Qg[(size_t)r * HDM + c];
  }
  __syncthreads();

  const bhalf8 aq0 = *(bhalf8*)&Qs[(wrow + ln15) * 72 + quad * 8];
  const bhalf8 aq1 = *(bhalf8*)&Qs[(wrow + ln15) * 72 + quad * 8 + 32];

  floatx4 o[4];
  float mrow[4], lrow[4];
#pragma unroll
  for (int c = 0; c < 4; ++c) o[c] = (floatx4){0.f, 0.f, 0.f, 0.f};
#pragma unroll
  for (int r = 0; r < 4; ++r) { mrow[r] = -1e30f; lrow[r] = 0.f; }

  const int jt0 = z * 16;
  // init carry = "fresh" of virtual iter jt0-1: band rows rbase(jt0)+64+[0,64),
  // B-frags one-time direct from global (rows <= 4095, within padded Tb).
  floatx4 carry[4];
  {
    int rb0 = i0 - jt0 * 64 + SEQ - HDM;
#pragma unroll
    for (int ct = 0; ct < 4; ++ct) {
      const bf16* tr = Tb + (size_t)(rb0 + 64 + ct * 16 + ln15) * HDM + quad * 8;
      bhalf8 b0 = *(const bhalf8*)tr;
      bhalf8 b1 = *(const bhalf8*)(tr + 32);
      floatx4 a = (floatx4){0.f, 0.f, 0.f, 0.f};
      a = __builtin_amdgcn_mfma_f32_16x16x32_bf16(aq0, b0, a, 0, 0, 0);
      a = __builtin_amdgcn_mfma_f32_16x16x32_bf16(aq1, b1, a, 0, 0, 0);
      carry[ct] = a;
    }
  }

  for (int jt = jt0; jt < jt0 + 16; ++jt) {
    const int j0 = jt * 64;
    const int rbase = i0 - j0 + SEQ - HDM;   // in [0, 3968]
    __syncthreads();   // staging regions safe (prev iter fully consumed)
#pragma unroll
    for (int t = 0; t < 2; ++t) {
      int id = tid + t * 256;
      int r = id >> 3, c = (id & 7) * 8;
      *(float4*)&Ks[r * 72 + c] = *(const float4*)&Kg[(size_t)(j0 + r) * HDM + c];
      *(float4*)&Vs[r * 72 + c] = *(const float4*)&Vg[(size_t)r * SEQ + j0 + c];
    }
    {
      int id = tid;
      int r = id >> 2, c = (id & 3) * 8;     // wait: 64 rows x 8 chunks = 512
    }
#pragma unroll
    for (int t = 0; t < 2; ++t) {
      int id = tid + t * 256;
      int r = id >> 3, c = (id & 7) * 8;     // Ts rows [rbase, rbase+64)
      *(float4*)&Ts[r * 72 + c] = *(const float4*)&Tb[(size_t)(rbase + r) * HDM + c];
    }
    __syncthreads();

    // S2 fresh half: band t in [0,64) (4 ct), wave-private S2c rows.
    // Scatter: fresh (row,t) -> col=row+63-t when t>=row (col in [row,63]);
    //          carry (row,t) -> col=row-1-t  when t< row (col in [0,row)).
    floatx4 fresh[4];
#pragma unroll
    for (int ct = 0; ct < 4; ++ct) {
      bhalf8 b0 = *(bhalf8*)&Ts[(ct * 16 + ln15) * 72 + quad * 8];
      bhalf8 b1 = *(bhalf8*)&Ts[(ct * 16 + ln15) * 72 + quad * 8 + 32];
      floatx4 a = (floatx4){0.f, 0.f, 0.f, 0.f};
      a = __builtin_amdgcn_mfma_f32_16x16x32_bf16(aq0, b0, a, 0, 0, 0);
      a = __builtin_amdgcn_mfma_f32_16x16x32_bf16(aq1, b1, a, 0, 0, 0);
      fresh[ct] = a;
    }
#pragma unroll
    for (int ct = 0; ct < 4; ++ct) {
      int t = ct * 16 + ln15;
#pragma unroll
      for (int r = 0; r < 4; ++r) {
        int row = wrow + quad * 4 + r;
        if (t >= row) S2c[row * 66 + (row + 63 - t)] = fresh[ct][r];
        else          S2c[row * 66 + (row - 1 - t)] = carry[ct][r];
      }
      carry[ct] = fresh[ct];
    }
    __syncthreads();   // all waves done with Ts -> Ps region reusable

    // S1 = Q K^T, add rel band (contiguous read), online softmax
    float sc[4][4];
#pragma unroll
    for (int ct = 0; ct < 4; ++ct) {
      bhalf8 b0 = *(bhalf8*)&Ks[(ct * 16 + ln15) * 72 + quad * 8];
      bhalf8 b1 = *(bhalf8*)&Ks[(ct * 16 + ln15) * 72 + quad * 8 + 32];
      floatx4 a = (floatx4){0.f, 0.f, 0.f, 0.f};
      a = __builtin_amdgcn_mfma_f32_16x16x32_bf16(aq0, b0, a, 0, 0, 0);
      a = __builtin_amdgcn_mfma_f32_16x16x32_bf16(aq1, b1, a, 0, 0, 0);
#pragma unroll
      for (int r = 0; r < 4; ++r) {
        int row = wrow + quad * 4 + r;
        sc[ct][r] = a[r] * 0.125f + S2c[row * 66 + ct * 16 + ln15];
      }
    }
#pragma unroll
    for (int r = 0; r < 4; ++r) {
      float tm = fmaxf(fmaxf(sc[0][r], sc[1][r]), fmaxf(sc[2][r], sc[3][r]));
      tm = fmaxf(tm, __shfl_xor(tm, 1));
      tm = fmaxf(tm, __shfl_xor(tm, 2));
      tm = fmaxf(tm, __shfl_xor(tm, 4));
      tm = fmaxf(tm, __shfl_xor(tm, 8));
      float mn = fmaxf(mrow[r], tm);
      float alpha = __expf(mrow[r] - mn);
      mrow[r] = mn;
      float rs = 0.f;
#pragma unroll
      for (int ct = 0; ct < 4; ++ct) {
        float p = __expf(sc[ct][r] - mn);
        sc[ct][r] = p;
        rs += p;
      }
      rs += __shfl_xor(rs, 1); rs += __shfl_xor(rs, 2);
      rs += __shfl_xor(rs, 4); rs += __shfl_xor(rs, 8);
      lrow[r] = lrow[r] * alpha + rs;
#pragma unroll
      for (int ct = 0; ct < 4; ++ct) o[ct][r] *= alpha;
    }
#pragma unroll
    for (int ct = 0; ct < 4; ++ct)
#pragma unroll
      for (int r = 0; r < 4; ++r)
        Ps[(wrow + quad * 4 + r) * 72 + ct * 16 + ln15] = __float2bfloat16(sc[ct][r]);

    bhalf8 ap0 = *(bhalf8*)&Ps[(wrow + ln15) * 72 + quad * 8];
    bhalf8 ap1 = *(bhalf8*)&Ps[(wrow + ln15) * 72 + quad * 8 + 32];
#pragma unroll
    for (int ct = 0; ct < 4; ++ct) {
      bhalf8 b0 = *(bhalf8*)&Vs[(ct * 16 + ln15) * 72 + quad * 8];
      bhalf8 b1 = *(bhalf8*)&Vs[(ct * 16 + ln15) * 72 + quad * 8 + 32];
      o[ct] = __builtin_amdgcn_mfma_f32_16x16x32_bf16(ap0, b0, o[ct], 0, 0, 0);
      o[ct] = __builtin_amdgcn_mfma_f32_16x16x32_bf16(ap1, b1, o[ct], 0, 0, 0);
    }
  }

  // epilogue: locally-normalized partial + (m,l)
  bf16* Oz = Opart + (size_t)z * SEQ * DM;
#pragma unroll
  for (int r = 0; r < 4; ++r) {
    float inv = 1.f / lrow[r];
    int row = i0 + wrow + quad * 4 + r;
#pragma unroll
    for (int ct = 0; ct < 4; ++ct)
      Oz[(size_t)row * DM + h * HDM + ct * 16 + ln15] =
          __float2bfloat16(o[ct][r] * inv);
    if (ln15 == 0) {
      float* mlp = ml + (((size_t)z * NH + h) * SEQ + row) * 2;
      mlp[0] = mrow[r];
      mlp[1] = lrow[r];
    }
  }
}

// ---- merge the two key-halves: O = w0*O0n + w1*O1n
__global__ __launch_bounds__(256) void attn_merge(
    const bf16* __restrict__ O0, const bf16* __restrict__ O1,
    const float* __restrict__ ml, bf16* __restrict__ O)
{
  const int i = blockIdx.x;
  const int tid = threadIdx.x;
  __shared__ float w0s[NH], w1s[NH];
  if (tid < NH) {
    const float* p0 = ml + (((size_t)0 * NH + tid) * SEQ + i) * 2;
    const float* p1 = ml + (((size_t)1 * NH + tid) * SEQ + i) * 2;
    float m0 = p0[0], l0 = p0[1], m1 = p1[0], l1 = p1[1];
    float m = fmaxf(m0, m1);
    float a = l0 * __expf(m0 - m), b = l1 * __expf(m1 - m);
    float inv = 1.f / (a + b);
    w0s[tid] = a * inv; w1s[tid] = b * inv;
  }
  __syncthreads();
  const int d = tid * 4;
  const float w0 = w0s[d >> 6], w1 = w1s[d >> 6];
  union { bf16 h[4]; float2 f; } a0, a1, ov;
  a0.f = *(const float2*)&O0[(size_t)i * DM + d];
  a1.f = *(const float2*)&O1[(size_t)i * DM + d];
#pragma unroll
  for (int e = 0; e < 4; ++e)
    ov.h[e] = __float2bfloat16(w0 * __bfloat162float(a0.h[e]) +
                               w1 * __bfloat162float(a1.h[e]));
  *(float2*)&O[(size_t)i * DM + d] = ov.f;
}

extern "C" void kernel_launch(void* const* d_in, const int* in_sizes, int n_in,
                              void* d_out, int out_size, void* d_ws, size_t ws_size,
                              hipStream_t stream) {
  const float* x   = (const float*)d_in[0];
  const float* Wq  = (const float*)d_in[1];
  const float* bq  = (const float*)d_in[2];
  const float* Wk  = (const float*)d_in[3];
  const float* bk  = (const float*)d_in[4];
  const float* Wv  = (const float*)d_in[5];
  const float* bv  = (const float*)d_in[6];
  const float* Wo  = (const float*)d_in[7];
  const float* bo  = (const float*)d_in[8];
  const float* rel = (const float*)d_in[9];
  float* out = (float*)d_out;

  const size_t SD = (size_t)SEQ * DM;      // 2M elems
  bf16* qws = (bf16*)d_ws;                 // [H][S][64]
  bf16* kws = qws + SD;                    // [H][S][64]
  bf16* vws = kws + SD;                    // Vt [D][S]
  bf16* ows = vws + SD;                    // [S][D] merged attn out
  bf16* xbf = ows + SD;                    // [S][D]
  bf16* wt  = xbf + SD;                    // 4 x [n][k] (q,k,v,o)
  bf16* tbf = wt + 4 * (size_t)DM * DM;    // [4096][64]
  bf16* opart = tbf + (size_t)4096 * HDM;  // 2 x [S][D] partials
  float* ml   = (float*)(opart + 2 * SD);  // [2][NH][SEQ][2]

  prep<<<3328, 256, 0, stream>>>(x, rel, Wq, Wk, Wv, Wo, xbf, tbf, wt);
  gemm_qkv<<<dim3(8, 32, 3), 256, 0, stream>>>(xbf, wt, bq, bk, bv, qws);
  attn_flash<<<dim3(SEQ / 64, NH, 2), 256, 0, stream>>>(qws, kws, vws, tbf,
                                                        opart, ml);
  attn_merge<<<SEQ, 256, 0, stream>>>(opart, opart + SD, ml, ows);
  gemm_out<<<dim3(8, 32), 256, 0, stream>>>(ows, wt + 3 * (size_t)DM * DM, bo, out);
}